// Round 13
// baseline (3476.771 us; speedup 1.0000x reference)
//
#include <hip/hip_runtime.h>
#include <math.h>

constexpr int NLAYER = 12;
constexpr int H = 768;
constexpr int NH = 12;
constexpr int DH = 64;
constexpr int T = 512;
constexpr int B = 4;
constexpr int K = 21;
constexpr int BT = B * T;
constexpr float NEGB = -10000.0f;
constexpr float LNEPS = 1e-12f;
constexpr float INV_SQRT_DH = 0.125f;

typedef __attribute__((ext_vector_type(8))) short bf16x8;
typedef __attribute__((ext_vector_type(4))) float f32x4;
typedef __attribute__((ext_vector_type(4))) unsigned short u16x4;

#define WAIT_VMCNT(n) asm volatile("s_waitcnt vmcnt(" #n ")")

// ---------------- helpers ----------------
__device__ __forceinline__ float wave_sum_f(float v) {
#pragma unroll
  for (int off = 32; off > 0; off >>= 1) v += __shfl_xor(v, off);
  return v;
}
__device__ __forceinline__ int wave_sum_i(int v) {
#pragma unroll
  for (int off = 32; off > 0; off >>= 1) v += __shfl_xor(v, off);
  return v;
}
__device__ __forceinline__ float readlane_f(float v, int i) {
  return __uint_as_float(__builtin_amdgcn_readlane(__float_as_uint(v), i));
}
__device__ __forceinline__ unsigned short f32_bf16_rn(float x) {
  unsigned int u = __float_as_uint(x);
  u += 0x7fffu + ((u >> 16) & 1u);
  return (unsigned short)(u >> 16);
}
__device__ __forceinline__ void split_bf16(float x, unsigned short& h, unsigned short& l) {
  h = f32_bf16_rn(x);
  float hf = __uint_as_float((unsigned int)h << 16);
  l = f32_bf16_rn(x - hf);
}
__device__ __forceinline__ void block_reduce_sum2(float& s, float& q) {
  __shared__ float red[8];
  s = wave_sum_f(s);
  q = wave_sum_f(q);
  int lane = threadIdx.x & 63, wid = threadIdx.x >> 6;
  if (lane == 0) { red[wid] = s; red[4 + wid] = q; }
  __syncthreads();
  s = red[0] + red[1] + red[2] + red[3];
  q = red[4] + red[5] + red[6] + red[7];
}

// ---------------- embedding + LN ----------------
__global__ __launch_bounds__(256) void embed_ln_kernel(
    const int* __restrict__ ids, const float* __restrict__ wemb,
    const float* __restrict__ pemb, const float* __restrict__ temb,
    const float* __restrict__ g, const float* __restrict__ bta,
    float* __restrict__ h, unsigned short* __restrict__ hh,
    unsigned short* __restrict__ hl) {
  int row = blockIdx.x;
  int t = row % T;
  int id = ids[row];
  const float* wp = wemb + (size_t)id * H;
  const float* pp = pemb + (size_t)t * H;
  float x[3];
  float s = 0.f, q = 0.f;
#pragma unroll
  for (int i = 0; i < 3; i++) {
    int c = threadIdx.x + i * 256;
    x[i] = wp[c] + pp[c] + temb[c];
    s += x[i];
    q += x[i] * x[i];
  }
  block_reduce_sum2(s, q);
  float mean = s * (1.0f / H);
  float var = q * (1.0f / H) - mean * mean;
  float inv = rsqrtf(var + LNEPS);
#pragma unroll
  for (int i = 0; i < 3; i++) {
    int c = threadIdx.x + i * 256;
    float y = (x[i] - mean) * inv * g[c] + bta[c];
    h[(size_t)row * H + c] = y;
    unsigned short yh, yl;
    split_bf16(y, yh, yl);
    hh[(size_t)row * H + c] = yh;
    hl[(size_t)row * H + c] = yl;
  }
}

// ---------------- residual add + LN ----------------
__global__ __launch_bounds__(256) void add_ln_kernel(
    float* __restrict__ h, const float* __restrict__ add,
    const float* __restrict__ g, const float* __restrict__ bta,
    unsigned short* __restrict__ hh, unsigned short* __restrict__ hl) {
  int row = blockIdx.x;
  size_t base = (size_t)row * H;
  float x[3];
  float s = 0.f, q = 0.f;
#pragma unroll
  for (int i = 0; i < 3; i++) {
    int c = threadIdx.x + i * 256;
    x[i] = h[base + c] + add[base + c];
    s += x[i];
    q += x[i] * x[i];
  }
  block_reduce_sum2(s, q);
  float mean = s * (1.0f / H);
  float var = q * (1.0f / H) - mean * mean;
  float inv = rsqrtf(var + LNEPS);
#pragma unroll
  for (int i = 0; i < 3; i++) {
    int c = threadIdx.x + i * 256;
    float y = (x[i] - mean) * inv * g[c] + bta[c];
    h[base + c] = y;
    unsigned short yh, yl;
    split_bf16(y, yh, yl);
    hh[base + c] = yh;
    hl[base + c] = yl;
  }
}

// ---------------- weight transpose+split body (one layer; 6912 blocks) ----------------
__device__ __forceinline__ void wconv_body(
    int bid, int tid, const float* __restrict__ w0, const float* __restrict__ w1,
    const float* __restrict__ w2, const float* __restrict__ w3,
    unsigned short* __restrict__ Wth, unsigned short* __restrict__ Wtl,
    float (*tile)[33]) {
  const float* src;
  int Kd, N, tk, tn;
  size_t off;
  if (bid < 1728) {
    src = w0; Kd = 768; N = 2304; tk = bid / 72; tn = bid % 72; off = 0;
  } else if (bid < 2304) {
    int t2 = bid - 1728; src = w1; Kd = 768; N = 768; tk = t2 / 24; tn = t2 % 24;
    off = 1769472;
  } else if (bid < 4608) {
    int t2 = bid - 2304; src = w2; Kd = 768; N = 3072; tk = t2 / 96; tn = t2 % 96;
    off = 2359296;
  } else {
    int t2 = bid - 4608; src = w3; Kd = 3072; N = 768; tk = t2 / 24; tn = t2 % 24;
    off = 4718592;
  }
  int k0 = tk * 32, n0 = tn * 32;
  int r = tid >> 3, c = (tid & 7) * 4;
  float4 v = *(const float4*)(src + (size_t)(k0 + r) * N + n0 + c);
  tile[r][c + 0] = v.x; tile[r][c + 1] = v.y; tile[r][c + 2] = v.z; tile[r][c + 3] = v.w;
  __syncthreads();
  u16x4 hv, lv;
#pragma unroll
  for (int q2 = 0; q2 < 4; q2++) {
    unsigned short sh, sl;
    split_bf16(tile[c + q2][r], sh, sl);
    hv[q2] = sh; lv[q2] = sl;
  }
  size_t dst = off + (size_t)(n0 + r) * Kd + k0 + c;
  *(u16x4*)(Wth + dst) = hv;
  *(u16x4*)(Wtl + dst) = lv;
}

__global__ __launch_bounds__(256) void wconv_kernel(
    const float* __restrict__ w0, const float* __restrict__ w1,
    const float* __restrict__ w2, const float* __restrict__ w3,
    unsigned short* __restrict__ Wth, unsigned short* __restrict__ Wtl) {
  __shared__ float tile[32][33];
  wconv_body(blockIdx.x, threadIdx.x, w0, w1, w2, w3, Wth, Wtl, tile);
}

// ---------------- bf16 3-term MFMA GEMM, BM=64 x BN=128 tiles ----------------
template <int OUTMODE>
__global__ __launch_bounds__(256) void gemm_bf3_kernel(
    const unsigned short* __restrict__ Ah, const unsigned short* __restrict__ Al,
    const unsigned short* __restrict__ Wth, const unsigned short* __restrict__ Wtl,
    const float* __restrict__ bias, float* __restrict__ C,
    unsigned short* __restrict__ Ch, unsigned short* __restrict__ Cl,
    unsigned short* __restrict__ Kh, unsigned short* __restrict__ Kl,
    unsigned short* __restrict__ Vth, unsigned short* __restrict__ Vtl,
    int N, int Kd, int ncols) {
  constexpr int AW = 64 * 32;
  constexpr int WW = 128 * 32;
  constexpr int DBS = 2 * AW + 2 * WW;
  __shared__ short lds_s[2 * DBS];
  int tid = threadIdx.x;
  int lane = tid & 63, wid = tid >> 6;
  int wr = wid >> 1, wc = wid & 1;
  int tiles = gridDim.x;
  int q8 = tiles >> 3;
  int wg = (blockIdx.x & 7) * q8 + (blockIdx.x >> 3);
  int bm = (wg / ncols) * 64, bn = (wg % ncols) * 128;

  f32x4 acc[2][4] = {};
  int lrow = lane >> 2;
  int lslot_sw = (lane & 3) ^ ((lrow >> 1) & 3);

  const unsigned short* sbase;
  int rowbase, ldsoff, nchunks;
  if (wid == 0)      { sbase = Ah;  rowbase = bm; ldsoff = 0;            nchunks = 4; }
  else if (wid == 1) { sbase = Al;  rowbase = bm; ldsoff = AW;           nchunks = 4; }
  else if (wid == 2) { sbase = Wth; rowbase = bn; ldsoff = 2 * AW;       nchunks = 8; }
  else               { sbase = Wtl; rowbase = bn; ldsoff = 2 * AW + WW;  nchunks = 8; }

  const unsigned short* srcbase = sbase + (size_t)(rowbase + lrow) * Kd + lslot_sw * 8;

  auto STAGE = [&](int db, int k0) {
#pragma unroll
    for (int c = 0; c < 8; c++) {
      if (c < nchunks) {
        const unsigned short* src = srcbase + (size_t)(c * 16) * Kd + k0;
        char* dst = ((char*)lds_s) + (db * DBS + ldsoff) * 2 + c * 1024 + lane * 16;
        __builtin_amdgcn_global_load_lds(
            (const __attribute__((address_space(1))) void*)src,
            (__attribute__((address_space(3))) void*)dst, 16, 0, 0);
      }
    }
  };

  const int NT = Kd / 32;
  STAGE(0, 0);
  for (int kt = 0; kt < NT; kt++) {
    int cur = kt & 1;
    bool more = (kt + 1 < NT);
    if (more) STAGE(cur ^ 1, (kt + 1) * 32);
    if (more) {
      if (wid < 2) { WAIT_VMCNT(4); } else { WAIT_VMCNT(8); }
    } else {
      WAIT_VMCNT(0);
    }
    __builtin_amdgcn_s_barrier();
    __builtin_amdgcn_sched_barrier(0);

    int lr = lane & 15, lg = lane >> 4;
    int slot = (lg ^ ((lr >> 1) & 3)) * 8;
    int cb = cur * DBS;
    bf16x8 af_h[2], af_l[2], wf_h[4], wf_l[4];
#pragma unroll
    for (int i = 0; i < 2; i++) {
      int e = (wr * 32 + i * 16 + lr) * 32 + slot;
      af_h[i] = *(const bf16x8*)&lds_s[cb + e];
      af_l[i] = *(const bf16x8*)&lds_s[cb + AW + e];
    }
#pragma unroll
    for (int j = 0; j < 4; j++) {
      int e = (wc * 64 + j * 16 + lr) * 32 + slot;
      wf_h[j] = *(const bf16x8*)&lds_s[cb + 2 * AW + e];
      wf_l[j] = *(const bf16x8*)&lds_s[cb + 2 * AW + WW + e];
    }
#pragma unroll
    for (int i = 0; i < 2; i++)
#pragma unroll
      for (int j = 0; j < 4; j++) {
        acc[i][j] = __builtin_amdgcn_mfma_f32_16x16x32_bf16(af_h[i], wf_h[j], acc[i][j], 0, 0, 0);
        acc[i][j] = __builtin_amdgcn_mfma_f32_16x16x32_bf16(af_l[i], wf_h[j], acc[i][j], 0, 0, 0);
        acc[i][j] = __builtin_amdgcn_mfma_f32_16x16x32_bf16(af_h[i], wf_l[j], acc[i][j], 0, 0, 0);
      }
    asm volatile("s_waitcnt lgkmcnt(0)");
    __builtin_amdgcn_sched_barrier(0);
    __builtin_amdgcn_s_barrier();
    __builtin_amdgcn_sched_barrier(0);
  }

  int lr = lane & 15, lg = lane >> 4;
#pragma unroll
  for (int i = 0; i < 2; i++) {
#pragma unroll
    for (int j = 0; j < 4; j++) {
      int row = bm + wr * 32 + i * 16 + lg * 4;
      int col = bn + wc * 64 + j * 16 + lr;
      float bv = bias[col];
      if (OUTMODE == 2) {
        int sec = col / 768;
        int within = col % 768;
        int hidx = within >> 6, d = within & 63;
        int b = row >> 9, t = row & 511;
        int bh = b * NH + hidx;
        if (sec == 2) {
          u16x4 hv, lv;
#pragma unroll
          for (int r = 0; r < 4; r++) {
            unsigned short sh, sl;
            split_bf16(acc[i][j][r] + bv, sh, sl);
            hv[r] = sh; lv[r] = sl;
          }
          size_t idx = ((size_t)bh * 64 + d) * T + t;
          *(u16x4*)(Vth + idx) = hv;
          *(u16x4*)(Vtl + idx) = lv;
        } else {
          unsigned short* dh = (sec == 0) ? Ch : Kh;
          unsigned short* dl = (sec == 0) ? Cl : Kl;
#pragma unroll
          for (int r = 0; r < 4; r++) {
            unsigned short sh, sl;
            split_bf16(acc[i][j][r] + bv, sh, sl);
            size_t idx = ((size_t)bh * T + t + r) * 64 + d;
            dh[idx] = sh;
            dl[idx] = sl;
          }
        }
      } else {
#pragma unroll
        for (int r = 0; r < 4; r++) {
          float v = acc[i][j][r] + bv;
          if (OUTMODE == 1) {
            v = 0.5f * v * (1.0f + erff(v * 0.70710678118654752f));
            unsigned short sh, sl;
            split_bf16(v, sh, sl);
            Ch[(size_t)(row + r) * N + col] = sh;
            Cl[(size_t)(row + r) * N + col] = sl;
          } else {
            C[(size_t)(row + r) * N + col] = v;
          }
        }
      }
    }
  }
}

// ---------------- fused attention (blocks 0..383) + next-layer wconv (384..) ----------------
// attn part identical to round-10's attn_kernel (XCD-clustered 1D grid).
__global__ __launch_bounds__(256) void attn_wconv_kernel(
    const unsigned short* __restrict__ qh, const unsigned short* __restrict__ ql,
    const unsigned short* __restrict__ kh, const unsigned short* __restrict__ kl,
    const unsigned short* __restrict__ vth, const unsigned short* __restrict__ vtl,
    const int* __restrict__ mask,
    unsigned short* __restrict__ cth, unsigned short* __restrict__ ctl,
    const float* __restrict__ nw0, const float* __restrict__ nw1,
    const float* __restrict__ nw2, const float* __restrict__ nw3,
    unsigned short* __restrict__ nWth, unsigned short* __restrict__ nWtl) {
  __shared__ float bias_s[T];
  __shared__ short p_h[4][16 * 64];
  __shared__ short p_l[4][16 * 64];
  int tid = threadIdx.x;

  if (blockIdx.x >= 384) {
    // next-layer weight conversion riding in attn's idle CUs (validated round 11)
    float (*tile)[33] = (float(*)[33]) & p_h[0][0];  // 4224B overlay
    wconv_body(blockIdx.x - 384, tid, nw0, nw1, nw2, nw3, nWth, nWtl, tile);
    return;
  }

  int id = blockIdx.x;
  int bh = (id & 7) * 6 + ((id >> 3) % 6);
  int i0 = (id / 48) * 64;
  int b = bh / NH, hidx = bh % NH;
  int lane = tid & 63, w = tid >> 6;
  int lr = lane & 15, lg = lane >> 4;
  for (int i = tid; i < T; i += 256)
    bias_s[i] = (1.0f - (float)mask[b * T + i]) * NEGB;
  __syncthreads();

  const unsigned short* qb_h = qh + ((size_t)bh * T + i0 + w * 16 + lr) * 64 + lg * 8;
  const unsigned short* qb_l = ql + ((size_t)bh * T + i0 + w * 16 + lr) * 64 + lg * 8;
  bf16x8 qf_h0 = *(const bf16x8*)qb_h;
  bf16x8 qf_h1 = *(const bf16x8*)(qb_h + 32);
  bf16x8 qf_l0 = *(const bf16x8*)qb_l;
  bf16x8 qf_l1 = *(const bf16x8*)(qb_l + 32);

  float m_run[4], l_run[4];
#pragma unroll
  for (int r = 0; r < 4; r++) { m_run[r] = -3.0e38f; l_run[r] = 0.f; }
  f32x4 acc_o[4] = {};

  for (int kt = 0; kt < T / 64; kt++) {
    f32x4 s[4] = {};
#pragma unroll
    for (int jf = 0; jf < 4; jf++) {
      size_t kb = ((size_t)bh * T + kt * 64 + jf * 16 + lr) * 64 + lg * 8;
      bf16x8 kf_h0 = *(const bf16x8*)(kh + kb);
      bf16x8 kf_h1 = *(const bf16x8*)(kh + kb + 32);
      bf16x8 kf_l0 = *(const bf16x8*)(kl + kb);
      bf16x8 kf_l1 = *(const bf16x8*)(kl + kb + 32);
      s[jf] = __builtin_amdgcn_mfma_f32_16x16x32_bf16(qf_h0, kf_h0, s[jf], 0, 0, 0);
      s[jf] = __builtin_amdgcn_mfma_f32_16x16x32_bf16(qf_h1, kf_h1, s[jf], 0, 0, 0);
      s[jf] = __builtin_amdgcn_mfma_f32_16x16x32_bf16(qf_l0, kf_h0, s[jf], 0, 0, 0);
      s[jf] = __builtin_amdgcn_mfma_f32_16x16x32_bf16(qf_l1, kf_h1, s[jf], 0, 0, 0);
      s[jf] = __builtin_amdgcn_mfma_f32_16x16x32_bf16(qf_h0, kf_l0, s[jf], 0, 0, 0);
      s[jf] = __builtin_amdgcn_mfma_f32_16x16x32_bf16(qf_h1, kf_l1, s[jf], 0, 0, 0);
    }
    float mt[4] = {-3.0e38f, -3.0e38f, -3.0e38f, -3.0e38f};
#pragma unroll
    for (int jf = 0; jf < 4; jf++) {
      float bcol = bias_s[kt * 64 + jf * 16 + lr];
#pragma unroll
      for (int r = 0; r < 4; r++) {
        float v = s[jf][r] * INV_SQRT_DH + bcol;
        s[jf][r] = v;
        mt[r] = fmaxf(mt[r], v);
      }
    }
#pragma unroll
    for (int r = 0; r < 4; r++) {
      mt[r] = fmaxf(mt[r], __shfl_xor(mt[r], 1));
      mt[r] = fmaxf(mt[r], __shfl_xor(mt[r], 2));
      mt[r] = fmaxf(mt[r], __shfl_xor(mt[r], 4));
      mt[r] = fmaxf(mt[r], __shfl_xor(mt[r], 8));
    }
#pragma unroll
    for (int r = 0; r < 4; r++) {
      float mn = fmaxf(m_run[r], mt[r]);
      float sc = __expf(m_run[r] - mn);
      m_run[r] = mn;
      l_run[r] *= sc;
#pragma unroll
      for (int jf = 0; jf < 4; jf++) acc_o[jf][r] *= sc;
    }
    float ps[4] = {0.f, 0.f, 0.f, 0.f};
#pragma unroll
    for (int jf = 0; jf < 4; jf++) {
#pragma unroll
      for (int r = 0; r < 4; r++) {
        float p = __expf(s[jf][r] - m_run[r]);
        ps[r] += p;
        unsigned short sh, sl;
        split_bf16(p, sh, sl);
        int q = lg * 4 + r;
        int col = jf * 16 + lr;
        int addr = q * 64 + (((col >> 3) ^ (q & 7)) << 3) + (col & 7);
        p_h[w][addr] = sh;
        p_l[w][addr] = sl;
      }
    }
#pragma unroll
    for (int r = 0; r < 4; r++) {
      ps[r] += __shfl_xor(ps[r], 1);
      ps[r] += __shfl_xor(ps[r], 2);
      ps[r] += __shfl_xor(ps[r], 4);
      ps[r] += __shfl_xor(ps[r], 8);
      l_run[r] += ps[r];
    }
#pragma unroll
    for (int c = 0; c < 2; c++) {
      int aaddr = lr * 64 + (((4 * c + lg) ^ (lr & 7)) << 3);
      bf16x8 pa_h = *(const bf16x8*)&p_h[w][aaddr];
      bf16x8 pa_l = *(const bf16x8*)&p_l[w][aaddr];
#pragma unroll
      for (int jf = 0; jf < 4; jf++) {
        size_t vb = ((size_t)bh * 64 + jf * 16 + lr) * T + kt * 64 + c * 32 + lg * 8;
        bf16x8 vf_h = *(const bf16x8*)(vth + vb);
        bf16x8 vf_l = *(const bf16x8*)(vtl + vb);
        acc_o[jf] = __builtin_amdgcn_mfma_f32_16x16x32_bf16(pa_h, vf_h, acc_o[jf], 0, 0, 0);
        acc_o[jf] = __builtin_amdgcn_mfma_f32_16x16x32_bf16(pa_l, vf_h, acc_o[jf], 0, 0, 0);
        acc_o[jf] = __builtin_amdgcn_mfma_f32_16x16x32_bf16(pa_h, vf_l, acc_o[jf], 0, 0, 0);
      }
    }
  }
  float inv[4];
#pragma unroll
  for (int r = 0; r < 4; r++) inv[r] = 1.0f / l_run[r];
#pragma unroll
  for (int jf = 0; jf < 4; jf++) {
#pragma unroll
    for (int r = 0; r < 4; r++) {
      float v = acc_o[jf][r] * inv[r];
      unsigned short sh, sl;
      split_bf16(v, sh, sl);
      size_t idx = ((size_t)(b * T) + i0 + w * 16 + lg * 4 + r) * H + hidx * 64 + jf * 16 + lr;
      cth[idx] = sh;
      ctl[idx] = sl;
    }
  }
}

// ---------------- classifier (WcT rows, float4 dot) ----------------
__global__ __launch_bounds__(256) void wct_kernel(
    const float* __restrict__ Wc, float* __restrict__ WcT) {
  int id = blockIdx.x * 256 + threadIdx.x;
  int k = id / H, d = id % H;
  WcT[id] = Wc[d * K + k];
}

__global__ __launch_bounds__(256) void classifier_kernel(
    const float* __restrict__ h, const float* __restrict__ WcT,
    const float* __restrict__ bc, float* __restrict__ em) {
  int id = blockIdx.x * 256 + threadIdx.x;
  if (id >= BT * K) return;
  int row = id / K, k = id % K;
  const float4* h4 = (const float4*)(h + (size_t)row * H);
  const float4* w4 = (const float4*)(WcT + (size_t)k * H);
  float acc = bc[k];
  for (int d = 0; d < H / 4; d++) {
    float4 a = h4[d], b = w4[d];
    acc = fmaf(a.x, b.x, acc);
    acc = fmaf(a.y, b.y, acc);
    acc = fmaf(a.z, b.z, acc);
    acc = fmaf(a.w, b.w, acc);
  }
  em[id] = acc;
}

// first-max merge (strict >, left/earlier index wins ties == jnp.argmax)
#define MRG(vo, io, va, ia, vb, ib) \
  float vo = ((vb) > (va)) ? (vb) : (va); \
  int io = ((vb) > (va)) ? (ib) : (ia);

// ---------------- fused CRF nll + viterbi (8 blocks: batch x role) ----------------
__global__ __launch_bounds__(64) void crf_fused_kernel(
    const float* __restrict__ em, const int* __restrict__ labels,
    const int* __restrict__ mask, const float* __restrict__ start,
    const float* __restrict__ endv, const float* __restrict__ trans,
    float* __restrict__ parts, float* __restrict__ outdec) {
  __shared__ float em_s[T * K];
  __shared__ int mask_s[T];
  __shared__ unsigned char hist_s[(T - 1) * K];
  __shared__ float sc_s[32];
  int b = blockIdx.x & 3;
  int role = blockIdx.x >> 2;
  int j = threadIdx.x;
  const float* eb = em + (size_t)b * T * K;
  for (int i = j; i < T * K / 4; i += 64)
    ((float4*)em_s)[i] = ((const float4*)eb)[i];
  for (int i = j; i < T; i += 64) mask_s[i] = mask[b * T + i];
  __syncthreads();
  bool act = (j < K);
  float tr[K];
#pragma unroll
  for (int i = 0; i < K; i++) tr[i] = act ? trans[i * K + j] : 0.f;

  int cntloc = 0;
  for (int t = j; t < T; t += 64) cntloc += mask_s[t];
  int cnt = wave_sum_i(cntloc);

  if (role == 0) {
    const int* tb = labels + b * T;
    float numloc = 0.f;
    for (int t = j; t < T; t += 64) {
      if (t >= 1 && mask_s[t]) {
        int tp = tb[t - 1], tc = tb[t];
        numloc += trans[tp * K + tc] + em_s[t * K + tc];
      }
    }
    float num = wave_sum_f(numloc);
    float etr[K];
#pragma unroll
    for (int i = 0; i < K; i++) etr[i] = __expf(tr[i]);
    float alpha = act ? (start[j] + em_s[j]) : 0.f;
    float emv = act ? em_s[K + j] : 0.f;
    for (int t = 1; t < cnt; t++) {
      float emv_n = (act && (t + 1) < cnt) ? em_s[(t + 1) * K + j] : 0.f;
      float m0 = readlane_f(alpha, 0);
      float ee = __expf(alpha - m0);
      float e0 = readlane_f(ee, 0),  e1 = readlane_f(ee, 1),  e2 = readlane_f(ee, 2);
      float e3 = readlane_f(ee, 3),  e4 = readlane_f(ee, 4),  e5 = readlane_f(ee, 5);
      float e6 = readlane_f(ee, 6),  e7 = readlane_f(ee, 7),  e8 = readlane_f(ee, 8);
      float e9 = readlane_f(ee, 9),  e10 = readlane_f(ee, 10), e11 = readlane_f(ee, 11);
      float e12 = readlane_f(ee, 12), e13 = readlane_f(ee, 13), e14 = readlane_f(ee, 14);
      float e15 = readlane_f(ee, 15), e16 = readlane_f(ee, 16), e17 = readlane_f(ee, 17);
      float e18 = readlane_f(ee, 18), e19 = readlane_f(ee, 19), e20 = readlane_f(ee, 20);
      float a0 = fmaf(e16, etr[16], fmaf(e12, etr[12], fmaf(e8, etr[8],  fmaf(e4, etr[4], e0 * etr[0]))));
      float a1 = fmaf(e17, etr[17], fmaf(e13, etr[13], fmaf(e9, etr[9],  fmaf(e5, etr[5], e1 * etr[1]))));
      float a2 = fmaf(e18, etr[18], fmaf(e14, etr[14], fmaf(e10, etr[10], fmaf(e6, etr[6], e2 * etr[2]))));
      float a3 = fmaf(e19, etr[19], fmaf(e15, etr[15], fmaf(e11, etr[11], fmaf(e7, etr[7], e3 * etr[3]))));
      float ssum = fmaf(e20, etr[20], (a0 + a1) + (a2 + a3));
      float nxt = __logf(ssum) + m0 + emv;
      if (act) alpha = nxt;
      emv = emv_n;
    }
    float aj = act ? (alpha + endv[j]) : -3.0e38f;
    float mm = aj;
#pragma unroll
    for (int off = 32; off > 0; off >>= 1) mm = fmaxf(mm, __shfl_xor(mm, off));
    float e2v = act ? __expf(aj - mm) : 0.f;
    float s2 = wave_sum_f(e2v);
    float den = __logf(s2) + mm;
    if (j == 0) {
      int tag0 = tb[0];
      float numtot = num + start[tag0] + em_s[tag0] + endv[tb[cnt - 1]];
      parts[b] = numtot - den;
    }
  } else {
    float score = act ? (start[j] + em_s[j]) : 0.f;
    float emv = act ? em_s[K + j] : 0.f;
    for (int t = 1; t < cnt; t++) {
      float emv_n = (act && (t + 1) < cnt) ? em_s[(t + 1) * K + j] : 0.f;
      float c0 = readlane_f(score, 0) + tr[0],   c1 = readlane_f(score, 1) + tr[1];
      float c2 = readlane_f(score, 2) + tr[2],   c3 = readlane_f(score, 3) + tr[3];
      float c4 = readlane_f(score, 4) + tr[4],   c5 = readlane_f(score, 5) + tr[5];
      float c6 = readlane_f(score, 6) + tr[6],   c7 = readlane_f(score, 7) + tr[7];
      float c8 = readlane_f(score, 8) + tr[8],   c9 = readlane_f(score, 9) + tr[9];
      float c10 = readlane_f(score, 10) + tr[10], c11 = readlane_f(score, 11) + tr[11];
      float c12 = readlane_f(score, 12) + tr[12], c13 = readlane_f(score, 13) + tr[13];
      float c14 = readlane_f(score, 14) + tr[14], c15 = readlane_f(score, 15) + tr[15];
      float c16 = readlane_f(score, 16) + tr[16], c17 = readlane_f(score, 17) + tr[17];
      float c18 = readlane_f(score, 18) + tr[18], c19 = readlane_f(score, 19) + tr[19];
      float c20 = readlane_f(score, 20) + tr[20];
      MRG(m0v, m0i, c0, 0, c1, 1)
      MRG(m1v, m1i, c2, 2, c3, 3)
      MRG(m2v, m2i, c4, 4, c5, 5)
      MRG(m3v, m3i, c6, 6, c7, 7)
      MRG(m4v, m4i, c8, 8, c9, 9)
      MRG(m5v, m5i, c10, 10, c11, 11)
      MRG(m6v, m6i, c12, 12, c13, 13)
      MRG(m7v, m7i, c14, 14, c15, 15)
      MRG(m8v, m8i, c16, 16, c17, 17)
      MRG(m9v, m9i, c18, 18, c19, 19)
      MRG(p0v, p0i, m0v, m0i, m1v, m1i)
      MRG(p1v, p1i, m2v, m2i, m3v, m3i)
      MRG(p2v, p2i, m4v, m4i, m5v, m5i)
      MRG(p3v, p3i, m6v, m6i, m7v, m7i)
      MRG(p4v, p4i, m8v, m8i, m9v, m9i)
      MRG(r0v, r0i, p0v, p0i, p1v, p1i)
      MRG(r1v, r1i, p2v, p2i, p3v, p3i)
      MRG(r2v, r2i, p4v, p4i, c20, 20)
      MRG(s0v, s0i, r0v, r0i, r1v, r1i)
      MRG(fv, fi, s0v, s0i, r2v, r2i)
      if (act) {
        hist_s[(t - 1) * K + j] = (unsigned char)fi;
        score = fv + emv;
      }
      emv = emv_n;
    }
    if (act) sc_s[j] = score + endv[j];
    __syncthreads();
    if (j == 0) {
      float best = -3.0e38f;
      int last = 0;
#pragma unroll
      for (int i = 0; i < K; i++)
        if (sc_s[i] > best) { best = sc_s[i]; last = i; }
      for (int t = cnt - 1; t < T; t++) outdec[b * T + t] = (float)last;
      int cur = last;
      for (int t = cnt - 1; t >= 1; t--) {
        cur = hist_s[(t - 1) * K + cur];
        outdec[b * T + (t - 1)] = (float)cur;
      }
    }
  }
}

__global__ void nll_final_kernel(const float* __restrict__ parts,
                                 float* __restrict__ out) {
  out[0] = -0.25f * (parts[0] + parts[1] + parts[2] + parts[3]);
}

// ---------------- host launcher ----------------
extern "C" void kernel_launch(void* const* d_in, const int* in_sizes, int n_in,
                              void* d_out, int out_size, void* d_ws, size_t ws_size,
                              hipStream_t stream) {
  (void)in_sizes; (void)n_in; (void)out_size; (void)ws_size;
  const int* ids    = (const int*)d_in[0];
  const int* amask  = (const int*)d_in[1];
  const int* labels = (const int*)d_in[3];
  const float* wemb = (const float*)d_in[4];
  const float* pemb = (const float*)d_in[5];
  const float* temb = (const float*)d_in[6];
  const float* eg   = (const float*)d_in[7];
  const float* ebta = (const float*)d_in[8];
  const float* Wqkv = (const float*)d_in[9];
  const float* bqkv = (const float*)d_in[10];
  const float* Wo   = (const float*)d_in[11];
  const float* bo   = (const float*)d_in[12];
  const float* ln1g = (const float*)d_in[13];
  const float* ln1b = (const float*)d_in[14];
  const float* W1   = (const float*)d_in[15];
  const float* b1   = (const float*)d_in[16];
  const float* W2   = (const float*)d_in[17];
  const float* b2   = (const float*)d_in[18];
  const float* ln2g = (const float*)d_in[19];
  const float* ln2b = (const float*)d_in[20];
  const float* Wc   = (const float*)d_in[21];
  const float* bc   = (const float*)d_in[22];
  const float* cst  = (const float*)d_in[23];
  const float* cen  = (const float*)d_in[24];
  const float* ctr  = (const float*)d_in[25];
  float* out = (float*)d_out;

  // workspace layout (float units)
  float* ws = (float*)d_ws;
  float* fp = ws;
  float* h = fp;                 fp += 1572864;
  unsigned short* hh  = (unsigned short*)fp; fp += 786432;
  unsigned short* hl  = (unsigned short*)fp; fp += 786432;
  unsigned short* qhp = (unsigned short*)fp; fp += 786432;
  unsigned short* qlp = (unsigned short*)fp; fp += 786432;
  unsigned short* khp = (unsigned short*)fp; fp += 786432;
  unsigned short* klp = (unsigned short*)fp; fp += 786432;
  unsigned short* vtp = (unsigned short*)fp; fp += 786432;
  unsigned short* vlp = (unsigned short*)fp; fp += 786432;
  unsigned short* cth = (unsigned short*)fp; fp += 786432;
  unsigned short* ctl = (unsigned short*)fp; fp += 786432;
  float* tmp = fp;               fp += 1572864;
  unsigned short* gh  = (unsigned short*)fp; fp += 3145728;
  unsigned short* gl  = (unsigned short*)fp; fp += 3145728;
  float* em = fp;                fp += 43008;
  float* parts = fp;             fp += 8;
  float* WcT = fp;               fp += 16128;
  // ping-pong per-layer split-weight buffers (28 MB each pair half; both L3-resident)
  unsigned short* wb0h = (unsigned short*)fp; fp += 3538944;
  unsigned short* wb0l = (unsigned short*)fp; fp += 3538944;
  unsigned short* wb1h = (unsigned short*)fp; fp += 3538944;
  unsigned short* wb1l = (unsigned short*)fp; fp += 3538944;

  embed_ln_kernel<<<BT, 256, 0, stream>>>(ids, wemb, pemb, temb, eg, ebta, h, hh, hl);
  wct_kernel<<<63, 256, 0, stream>>>(Wc, WcT);
  // layer-0 weights converted standalone
  wconv_kernel<<<6912, 256, 0, stream>>>(Wqkv, Wo, W1, W2, wb0h, wb0l);

  for (int l = 0; l < NLAYER; l++) {
    const float* bqkv_l = bqkv + (size_t)l * 3 * H;
    const float* bo_l   = bo + (size_t)l * H;
    const float* b1_l   = b1 + (size_t)l * 4 * H;
    const float* b2_l   = b2 + (size_t)l * H;
    unsigned short* Wth = (l & 1) ? wb1h : wb0h;
    unsigned short* Wtl = (l & 1) ? wb1l : wb0l;
    unsigned short* nWth = (l & 1) ? wb0h : wb1h;
    unsigned short* nWtl = (l & 1) ? wb0l : wb1l;
    int ln = (l + 1 < NLAYER) ? l + 1 : l;  // clamped (unused when grid==384)

    // QKV projection (M=2048, N=2304): 576 tiles
    gemm_bf3_kernel<2><<<576, 256, 0, stream>>>(
        hh, hl, Wth, Wtl, bqkv_l, nullptr, qhp, qlp, khp, klp,
        vtp, vlp, 3 * H, H, 18);
    // fused attention + next-layer weight conversion
    int agrid = (l + 1 < NLAYER) ? (384 + 6912) : 384;
    attn_wconv_kernel<<<agrid, 256, 0, stream>>>(
        qhp, qlp, khp, klp, vtp, vlp, amask, cth, ctl,
        Wqkv + (size_t)ln * H * 3 * H, Wo + (size_t)ln * H * H,
        W1 + (size_t)ln * H * 4 * H, W2 + (size_t)ln * 4 * H * H, nWth, nWtl);
    // output projection (N=768): 192 tiles
    gemm_bf3_kernel<0><<<192, 256, 0, stream>>>(
        cth, ctl, Wth + 1769472, Wtl + 1769472, bo_l, tmp,
        nullptr, nullptr, nullptr, nullptr, nullptr, nullptr, H, H, 6);
    add_ln_kernel<<<BT, 256, 0, stream>>>(h, tmp, ln1g + (size_t)l * H, ln1b + (size_t)l * H, hh, hl);
    // FFN1 (N=3072): 768 tiles
    gemm_bf3_kernel<1><<<768, 256, 0, stream>>>(
        hh, hl, Wth + 2359296, Wtl + 2359296, b1_l, nullptr, gh, gl,
        nullptr, nullptr, nullptr, nullptr, 4 * H, H, 24);
    // FFN2 (N=768, K=3072): 192 tiles
    gemm_bf3_kernel<0><<<192, 256, 0, stream>>>(
        gh, gl, Wth + 4718592, Wtl + 4718592, b2_l, tmp,
        nullptr, nullptr, nullptr, nullptr, nullptr, nullptr, H, 4 * H, 6);
    add_ln_kernel<<<BT, 256, 0, stream>>>(h, tmp, ln2g + (size_t)l * H, ln2b + (size_t)l * H, hh, hl);
  }

  classifier_kernel<<<(BT * K + 255) / 256, 256, 0, stream>>>(h, WcT, bc, em);
  crf_fused_kernel<<<8, 64, 0, stream>>>(em, labels, amask, cst, cen, ctr, parts, out + 1);
  nll_final_kernel<<<1, 1, 0, stream>>>(parts, out);
}

// Round 14
// 3151.861 us; speedup vs baseline: 1.1031x; 1.1031x over previous
//
#include <hip/hip_runtime.h>
#include <math.h>

constexpr int NLAYER = 12;
constexpr int H = 768;
constexpr int NH = 12;
constexpr int DH = 64;
constexpr int T = 512;
constexpr int B = 4;
constexpr int K = 21;
constexpr int BT = B * T;
constexpr float NEGB = -10000.0f;
constexpr float LNEPS = 1e-12f;
constexpr float INV_SQRT_DH = 0.125f;

typedef __attribute__((ext_vector_type(8))) short bf16x8;
typedef __attribute__((ext_vector_type(4))) float f32x4;
typedef __attribute__((ext_vector_type(4))) unsigned short u16x4;

#define WAIT_VMCNT(n) asm volatile("s_waitcnt vmcnt(" #n ")")

// ---------------- helpers ----------------
__device__ __forceinline__ float wave_sum_f(float v) {
#pragma unroll
  for (int off = 32; off > 0; off >>= 1) v += __shfl_xor(v, off);
  return v;
}
__device__ __forceinline__ int wave_sum_i(int v) {
#pragma unroll
  for (int off = 32; off > 0; off >>= 1) v += __shfl_xor(v, off);
  return v;
}
__device__ __forceinline__ float readlane_f(float v, int i) {
  return __uint_as_float(__builtin_amdgcn_readlane(__float_as_uint(v), i));
}
__device__ __forceinline__ unsigned short f32_bf16_rn(float x) {
  unsigned int u = __float_as_uint(x);
  u += 0x7fffu + ((u >> 16) & 1u);
  return (unsigned short)(u >> 16);
}
__device__ __forceinline__ void split_bf16(float x, unsigned short& h, unsigned short& l) {
  h = f32_bf16_rn(x);
  float hf = __uint_as_float((unsigned int)h << 16);
  l = f32_bf16_rn(x - hf);
}
__device__ __forceinline__ void block_reduce_sum2(float& s, float& q) {
  __shared__ float red[8];
  s = wave_sum_f(s);
  q = wave_sum_f(q);
  int lane = threadIdx.x & 63, wid = threadIdx.x >> 6;
  if (lane == 0) { red[wid] = s; red[4 + wid] = q; }
  __syncthreads();
  s = red[0] + red[1] + red[2] + red[3];
  q = red[4] + red[5] + red[6] + red[7];
}

// ---------------- embedding + LN ----------------
__global__ __launch_bounds__(256) void embed_ln_kernel(
    const int* __restrict__ ids, const float* __restrict__ wemb,
    const float* __restrict__ pemb, const float* __restrict__ temb,
    const float* __restrict__ g, const float* __restrict__ bta,
    float* __restrict__ h, unsigned short* __restrict__ hh,
    unsigned short* __restrict__ hl) {
  int row = blockIdx.x;
  int t = row % T;
  int id = ids[row];
  const float* wp = wemb + (size_t)id * H;
  const float* pp = pemb + (size_t)t * H;
  float x[3];
  float s = 0.f, q = 0.f;
#pragma unroll
  for (int i = 0; i < 3; i++) {
    int c = threadIdx.x + i * 256;
    x[i] = wp[c] + pp[c] + temb[c];
    s += x[i];
    q += x[i] * x[i];
  }
  block_reduce_sum2(s, q);
  float mean = s * (1.0f / H);
  float var = q * (1.0f / H) - mean * mean;
  float inv = rsqrtf(var + LNEPS);
#pragma unroll
  for (int i = 0; i < 3; i++) {
    int c = threadIdx.x + i * 256;
    float y = (x[i] - mean) * inv * g[c] + bta[c];
    h[(size_t)row * H + c] = y;
    unsigned short yh, yl;
    split_bf16(y, yh, yl);
    hh[(size_t)row * H + c] = yh;
    hl[(size_t)row * H + c] = yl;
  }
}

// ---------------- residual add + LN ----------------
__global__ __launch_bounds__(256) void add_ln_kernel(
    float* __restrict__ h, const float* __restrict__ add,
    const float* __restrict__ g, const float* __restrict__ bta,
    unsigned short* __restrict__ hh, unsigned short* __restrict__ hl) {
  int row = blockIdx.x;
  size_t base = (size_t)row * H;
  float x[3];
  float s = 0.f, q = 0.f;
#pragma unroll
  for (int i = 0; i < 3; i++) {
    int c = threadIdx.x + i * 256;
    x[i] = h[base + c] + add[base + c];
    s += x[i];
    q += x[i] * x[i];
  }
  block_reduce_sum2(s, q);
  float mean = s * (1.0f / H);
  float var = q * (1.0f / H) - mean * mean;
  float inv = rsqrtf(var + LNEPS);
#pragma unroll
  for (int i = 0; i < 3; i++) {
    int c = threadIdx.x + i * 256;
    float y = (x[i] - mean) * inv * g[c] + bta[c];
    h[base + c] = y;
    unsigned short yh, yl;
    split_bf16(y, yh, yl);
    hh[base + c] = yh;
    hl[base + c] = yl;
  }
}

// ---------------- per-layer weight transpose + split (L3-resident reuse) ----------------
__global__ __launch_bounds__(256) void wconv_kernel(
    const float* __restrict__ w0, const float* __restrict__ w1,
    const float* __restrict__ w2, const float* __restrict__ w3,
    unsigned short* __restrict__ Wth, unsigned short* __restrict__ Wtl) {
  __shared__ float tile[32][33];
  int bid = blockIdx.x;
  const float* src;
  int Kd, N, tk, tn;
  size_t off;
  if (bid < 1728) {
    src = w0; Kd = 768; N = 2304; tk = bid / 72; tn = bid % 72; off = 0;
  } else if (bid < 2304) {
    int t2 = bid - 1728; src = w1; Kd = 768; N = 768; tk = t2 / 24; tn = t2 % 24;
    off = 1769472;
  } else if (bid < 4608) {
    int t2 = bid - 2304; src = w2; Kd = 768; N = 3072; tk = t2 / 96; tn = t2 % 96;
    off = 2359296;
  } else {
    int t2 = bid - 4608; src = w3; Kd = 3072; N = 768; tk = t2 / 24; tn = t2 % 24;
    off = 4718592;
  }
  int tid = threadIdx.x;
  int k0 = tk * 32, n0 = tn * 32;
  int r = tid >> 3, c = (tid & 7) * 4;
  float4 v = *(const float4*)(src + (size_t)(k0 + r) * N + n0 + c);
  tile[r][c + 0] = v.x; tile[r][c + 1] = v.y; tile[r][c + 2] = v.z; tile[r][c + 3] = v.w;
  __syncthreads();
  u16x4 hv, lv;
#pragma unroll
  for (int q2 = 0; q2 < 4; q2++) {
    unsigned short sh, sl;
    split_bf16(tile[c + q2][r], sh, sl);
    hv[q2] = sh; lv[q2] = sl;
  }
  size_t dst = off + (size_t)(n0 + r) * Kd + k0 + c;
  *(u16x4*)(Wth + dst) = hv;
  *(u16x4*)(Wtl + dst) = lv;
}

// ---------------- bf16 3-term MFMA GEMM, BM=64 x BN=128 tiles ----------------
template <int OUTMODE>
__global__ __launch_bounds__(256) void gemm_bf3_kernel(
    const unsigned short* __restrict__ Ah, const unsigned short* __restrict__ Al,
    const unsigned short* __restrict__ Wth, const unsigned short* __restrict__ Wtl,
    const float* __restrict__ bias, float* __restrict__ C,
    unsigned short* __restrict__ Ch, unsigned short* __restrict__ Cl,
    unsigned short* __restrict__ Kh, unsigned short* __restrict__ Kl,
    unsigned short* __restrict__ Vth, unsigned short* __restrict__ Vtl,
    int N, int Kd, int ncols) {
  constexpr int AW = 64 * 32;
  constexpr int WW = 128 * 32;
  constexpr int DBS = 2 * AW + 2 * WW;
  __shared__ short lds_s[2 * DBS];
  int tid = threadIdx.x;
  int lane = tid & 63, wid = tid >> 6;
  int wr = wid >> 1, wc = wid & 1;
  int tiles = gridDim.x;
  int q8 = tiles >> 3;
  int wg = (blockIdx.x & 7) * q8 + (blockIdx.x >> 3);
  int bm = (wg / ncols) * 64, bn = (wg % ncols) * 128;

  f32x4 acc[2][4] = {};
  int lrow = lane >> 2;
  int lslot_sw = (lane & 3) ^ ((lrow >> 1) & 3);

  const unsigned short* sbase;
  int rowbase, ldsoff, nchunks;
  if (wid == 0)      { sbase = Ah;  rowbase = bm; ldsoff = 0;            nchunks = 4; }
  else if (wid == 1) { sbase = Al;  rowbase = bm; ldsoff = AW;           nchunks = 4; }
  else if (wid == 2) { sbase = Wth; rowbase = bn; ldsoff = 2 * AW;       nchunks = 8; }
  else               { sbase = Wtl; rowbase = bn; ldsoff = 2 * AW + WW;  nchunks = 8; }

  const unsigned short* srcbase = sbase + (size_t)(rowbase + lrow) * Kd + lslot_sw * 8;

  auto STAGE = [&](int db, int k0) {
#pragma unroll
    for (int c = 0; c < 8; c++) {
      if (c < nchunks) {
        const unsigned short* src = srcbase + (size_t)(c * 16) * Kd + k0;
        char* dst = ((char*)lds_s) + (db * DBS + ldsoff) * 2 + c * 1024 + lane * 16;
        __builtin_amdgcn_global_load_lds(
            (const __attribute__((address_space(1))) void*)src,
            (__attribute__((address_space(3))) void*)dst, 16, 0, 0);
      }
    }
  };

  const int NT = Kd / 32;
  STAGE(0, 0);
  for (int kt = 0; kt < NT; kt++) {
    int cur = kt & 1;
    bool more = (kt + 1 < NT);
    if (more) STAGE(cur ^ 1, (kt + 1) * 32);
    if (more) {
      if (wid < 2) { WAIT_VMCNT(4); } else { WAIT_VMCNT(8); }
    } else {
      WAIT_VMCNT(0);
    }
    __builtin_amdgcn_s_barrier();
    __builtin_amdgcn_sched_barrier(0);

    int lr = lane & 15, lg = lane >> 4;
    int slot = (lg ^ ((lr >> 1) & 3)) * 8;
    int cb = cur * DBS;
    bf16x8 af_h[2], af_l[2], wf_h[4], wf_l[4];
#pragma unroll
    for (int i = 0; i < 2; i++) {
      int e = (wr * 32 + i * 16 + lr) * 32 + slot;
      af_h[i] = *(const bf16x8*)&lds_s[cb + e];
      af_l[i] = *(const bf16x8*)&lds_s[cb + AW + e];
    }
#pragma unroll
    for (int j = 0; j < 4; j++) {
      int e = (wc * 64 + j * 16 + lr) * 32 + slot;
      wf_h[j] = *(const bf16x8*)&lds_s[cb + 2 * AW + e];
      wf_l[j] = *(const bf16x8*)&lds_s[cb + 2 * AW + WW + e];
    }
#pragma unroll
    for (int i = 0; i < 2; i++)
#pragma unroll
      for (int j = 0; j < 4; j++) {
        acc[i][j] = __builtin_amdgcn_mfma_f32_16x16x32_bf16(af_h[i], wf_h[j], acc[i][j], 0, 0, 0);
        acc[i][j] = __builtin_amdgcn_mfma_f32_16x16x32_bf16(af_l[i], wf_h[j], acc[i][j], 0, 0, 0);
        acc[i][j] = __builtin_amdgcn_mfma_f32_16x16x32_bf16(af_h[i], wf_l[j], acc[i][j], 0, 0, 0);
      }
    asm volatile("s_waitcnt lgkmcnt(0)");
    __builtin_amdgcn_sched_barrier(0);
    __builtin_amdgcn_s_barrier();
    __builtin_amdgcn_sched_barrier(0);
  }

  int lr = lane & 15, lg = lane >> 4;
#pragma unroll
  for (int i = 0; i < 2; i++) {
#pragma unroll
    for (int j = 0; j < 4; j++) {
      int row = bm + wr * 32 + i * 16 + lg * 4;
      int col = bn + wc * 64 + j * 16 + lr;
      float bv = bias[col];
      if (OUTMODE == 2) {
        int sec = col / 768;
        int within = col % 768;
        int hidx = within >> 6, d = within & 63;
        int b = row >> 9, t = row & 511;
        int bh = b * NH + hidx;
        if (sec == 2) {
          u16x4 hv, lv;
#pragma unroll
          for (int r = 0; r < 4; r++) {
            unsigned short sh, sl;
            split_bf16(acc[i][j][r] + bv, sh, sl);
            hv[r] = sh; lv[r] = sl;
          }
          size_t idx = ((size_t)bh * 64 + d) * T + t;
          *(u16x4*)(Vth + idx) = hv;
          *(u16x4*)(Vtl + idx) = lv;
        } else {
          unsigned short* dh = (sec == 0) ? Ch : Kh;
          unsigned short* dl = (sec == 0) ? Cl : Kl;
#pragma unroll
          for (int r = 0; r < 4; r++) {
            unsigned short sh, sl;
            split_bf16(acc[i][j][r] + bv, sh, sl);
            size_t idx = ((size_t)bh * T + t + r) * 64 + d;
            dh[idx] = sh;
            dl[idx] = sl;
          }
        }
      } else {
#pragma unroll
        for (int r = 0; r < 4; r++) {
          float v = acc[i][j][r] + bv;
          if (OUTMODE == 1) {
            v = 0.5f * v * (1.0f + erff(v * 0.70710678118654752f));
            unsigned short sh, sl;
            split_bf16(v, sh, sl);
            Ch[(size_t)(row + r) * N + col] = sh;
            Cl[(size_t)(row + r) * N + col] = sl;
          } else {
            C[(size_t)(row + r) * N + col] = v;
          }
        }
      }
    }
  }
}

// ---------------- fused attention: online softmax, split-bf16 MFMA ----------------
// 1D grid (384). XCD-clustering swizzle: bh = (id&7)*6 + (id>>3)%6, qt = id/48
// (bijective; each XCD owns 6 whole heads -> K/V stays L2-local).
__global__ __launch_bounds__(256) void attn_kernel(
    const unsigned short* __restrict__ qh, const unsigned short* __restrict__ ql,
    const unsigned short* __restrict__ kh, const unsigned short* __restrict__ kl,
    const unsigned short* __restrict__ vth, const unsigned short* __restrict__ vtl,
    const int* __restrict__ mask,
    unsigned short* __restrict__ cth, unsigned short* __restrict__ ctl) {
  int id = blockIdx.x;
  int bh = (id & 7) * 6 + ((id >> 3) % 6);
  int i0 = (id / 48) * 64;
  int b = bh / NH, hidx = bh % NH;
  int tid = threadIdx.x, lane = tid & 63, w = tid >> 6;
  int lr = lane & 15, lg = lane >> 4;
  __shared__ float bias_s[T];
  __shared__ short p_h[4][16 * 64];
  __shared__ short p_l[4][16 * 64];
  for (int i = tid; i < T; i += 256)
    bias_s[i] = (1.0f - (float)mask[b * T + i]) * NEGB;
  __syncthreads();

  const unsigned short* qb_h = qh + ((size_t)bh * T + i0 + w * 16 + lr) * 64 + lg * 8;
  const unsigned short* qb_l = ql + ((size_t)bh * T + i0 + w * 16 + lr) * 64 + lg * 8;
  bf16x8 qf_h0 = *(const bf16x8*)qb_h;
  bf16x8 qf_h1 = *(const bf16x8*)(qb_h + 32);
  bf16x8 qf_l0 = *(const bf16x8*)qb_l;
  bf16x8 qf_l1 = *(const bf16x8*)(qb_l + 32);

  float m_run[4], l_run[4];
#pragma unroll
  for (int r = 0; r < 4; r++) { m_run[r] = -3.0e38f; l_run[r] = 0.f; }
  f32x4 acc_o[4] = {};

  for (int kt = 0; kt < T / 64; kt++) {
    f32x4 s[4] = {};
#pragma unroll
    for (int jf = 0; jf < 4; jf++) {
      size_t kb = ((size_t)bh * T + kt * 64 + jf * 16 + lr) * 64 + lg * 8;
      bf16x8 kf_h0 = *(const bf16x8*)(kh + kb);
      bf16x8 kf_h1 = *(const bf16x8*)(kh + kb + 32);
      bf16x8 kf_l0 = *(const bf16x8*)(kl + kb);
      bf16x8 kf_l1 = *(const bf16x8*)(kl + kb + 32);
      s[jf] = __builtin_amdgcn_mfma_f32_16x16x32_bf16(qf_h0, kf_h0, s[jf], 0, 0, 0);
      s[jf] = __builtin_amdgcn_mfma_f32_16x16x32_bf16(qf_h1, kf_h1, s[jf], 0, 0, 0);
      s[jf] = __builtin_amdgcn_mfma_f32_16x16x32_bf16(qf_l0, kf_h0, s[jf], 0, 0, 0);
      s[jf] = __builtin_amdgcn_mfma_f32_16x16x32_bf16(qf_l1, kf_h1, s[jf], 0, 0, 0);
      s[jf] = __builtin_amdgcn_mfma_f32_16x16x32_bf16(qf_h0, kf_l0, s[jf], 0, 0, 0);
      s[jf] = __builtin_amdgcn_mfma_f32_16x16x32_bf16(qf_h1, kf_l1, s[jf], 0, 0, 0);
    }
    float mt[4] = {-3.0e38f, -3.0e38f, -3.0e38f, -3.0e38f};
#pragma unroll
    for (int jf = 0; jf < 4; jf++) {
      float bcol = bias_s[kt * 64 + jf * 16 + lr];
#pragma unroll
      for (int r = 0; r < 4; r++) {
        float v = s[jf][r] * INV_SQRT_DH + bcol;
        s[jf][r] = v;
        mt[r] = fmaxf(mt[r], v);
      }
    }
#pragma unroll
    for (int r = 0; r < 4; r++) {
      mt[r] = fmaxf(mt[r], __shfl_xor(mt[r], 1));
      mt[r] = fmaxf(mt[r], __shfl_xor(mt[r], 2));
      mt[r] = fmaxf(mt[r], __shfl_xor(mt[r], 4));
      mt[r] = fmaxf(mt[r], __shfl_xor(mt[r], 8));
    }
#pragma unroll
    for (int r = 0; r < 4; r++) {
      float mn = fmaxf(m_run[r], mt[r]);
      float sc = __expf(m_run[r] - mn);
      m_run[r] = mn;
      l_run[r] *= sc;
#pragma unroll
      for (int jf = 0; jf < 4; jf++) acc_o[jf][r] *= sc;
    }
    float ps[4] = {0.f, 0.f, 0.f, 0.f};
#pragma unroll
    for (int jf = 0; jf < 4; jf++) {
#pragma unroll
      for (int r = 0; r < 4; r++) {
        float p = __expf(s[jf][r] - m_run[r]);
        ps[r] += p;
        unsigned short sh, sl;
        split_bf16(p, sh, sl);
        int q = lg * 4 + r;
        int col = jf * 16 + lr;
        int addr = q * 64 + (((col >> 3) ^ (q & 7)) << 3) + (col & 7);
        p_h[w][addr] = sh;
        p_l[w][addr] = sl;
      }
    }
#pragma unroll
    for (int r = 0; r < 4; r++) {
      ps[r] += __shfl_xor(ps[r], 1);
      ps[r] += __shfl_xor(ps[r], 2);
      ps[r] += __shfl_xor(ps[r], 4);
      ps[r] += __shfl_xor(ps[r], 8);
      l_run[r] += ps[r];
    }
#pragma unroll
    for (int c = 0; c < 2; c++) {
      int aaddr = lr * 64 + (((4 * c + lg) ^ (lr & 7)) << 3);
      bf16x8 pa_h = *(const bf16x8*)&p_h[w][aaddr];
      bf16x8 pa_l = *(const bf16x8*)&p_l[w][aaddr];
#pragma unroll
      for (int jf = 0; jf < 4; jf++) {
        size_t vb = ((size_t)bh * 64 + jf * 16 + lr) * T + kt * 64 + c * 32 + lg * 8;
        bf16x8 vf_h = *(const bf16x8*)(vth + vb);
        bf16x8 vf_l = *(const bf16x8*)(vtl + vb);
        acc_o[jf] = __builtin_amdgcn_mfma_f32_16x16x32_bf16(pa_h, vf_h, acc_o[jf], 0, 0, 0);
        acc_o[jf] = __builtin_amdgcn_mfma_f32_16x16x32_bf16(pa_l, vf_h, acc_o[jf], 0, 0, 0);
        acc_o[jf] = __builtin_amdgcn_mfma_f32_16x16x32_bf16(pa_h, vf_l, acc_o[jf], 0, 0, 0);
      }
    }
  }
  float inv[4];
#pragma unroll
  for (int r = 0; r < 4; r++) inv[r] = 1.0f / l_run[r];
#pragma unroll
  for (int jf = 0; jf < 4; jf++) {
#pragma unroll
    for (int r = 0; r < 4; r++) {
      float v = acc_o[jf][r] * inv[r];
      unsigned short sh, sl;
      split_bf16(v, sh, sl);
      size_t idx = ((size_t)(b * T) + i0 + w * 16 + lg * 4 + r) * H + hidx * 64 + jf * 16 + lr;
      cth[idx] = sh;
      ctl[idx] = sl;
    }
  }
}

// ---------------- classifier (WcT rows, float4 dot) ----------------
__global__ __launch_bounds__(256) void wct_kernel(
    const float* __restrict__ Wc, float* __restrict__ WcT) {
  int id = blockIdx.x * 256 + threadIdx.x;
  int k = id / H, d = id % H;
  WcT[id] = Wc[d * K + k];
}

__global__ __launch_bounds__(256) void classifier_kernel(
    const float* __restrict__ h, const float* __restrict__ WcT,
    const float* __restrict__ bc, float* __restrict__ em) {
  int id = blockIdx.x * 256 + threadIdx.x;
  if (id >= BT * K) return;
  int row = id / K, k = id % K;
  const float4* h4 = (const float4*)(h + (size_t)row * H);
  const float4* w4 = (const float4*)(WcT + (size_t)k * H);
  float acc = bc[k];
  for (int d = 0; d < H / 4; d++) {
    float4 a = h4[d], b = w4[d];
    acc = fmaf(a.x, b.x, acc);
    acc = fmaf(a.y, b.y, acc);
    acc = fmaf(a.z, b.z, acc);
    acc = fmaf(a.w, b.w, acc);
  }
  em[id] = acc;
}

// first-max merge (strict >, left/earlier index wins ties == jnp.argmax)
#define MRG(vo, io, va, ia, vb, ib) \
  float vo = ((vb) > (va)) ? (vb) : (va); \
  int io = ((vb) > (va)) ? (ib) : (ia);

// ---------------- fused CRF nll + viterbi (8 blocks: batch x role) ----------------
__global__ __launch_bounds__(64) void crf_fused_kernel(
    const float* __restrict__ em, const int* __restrict__ labels,
    const int* __restrict__ mask, const float* __restrict__ start,
    const float* __restrict__ endv, const float* __restrict__ trans,
    float* __restrict__ parts, float* __restrict__ outdec) {
  __shared__ float em_s[T * K];
  __shared__ int mask_s[T];
  __shared__ unsigned char hist_s[(T - 1) * K];
  __shared__ float sc_s[32];
  int b = blockIdx.x & 3;
  int role = blockIdx.x >> 2;
  int j = threadIdx.x;
  const float* eb = em + (size_t)b * T * K;
  for (int i = j; i < T * K / 4; i += 64)
    ((float4*)em_s)[i] = ((const float4*)eb)[i];
  for (int i = j; i < T; i += 64) mask_s[i] = mask[b * T + i];
  __syncthreads();
  bool act = (j < K);
  float tr[K];
#pragma unroll
  for (int i = 0; i < K; i++) tr[i] = act ? trans[i * K + j] : 0.f;

  int cntloc = 0;
  for (int t = j; t < T; t += 64) cntloc += mask_s[t];
  int cnt = wave_sum_i(cntloc);

  if (role == 0) {
    const int* tb = labels + b * T;
    float numloc = 0.f;
    for (int t = j; t < T; t += 64) {
      if (t >= 1 && mask_s[t]) {
        int tp = tb[t - 1], tc = tb[t];
        numloc += trans[tp * K + tc] + em_s[t * K + tc];
      }
    }
    float num = wave_sum_f(numloc);
    float etr[K];
#pragma unroll
    for (int i = 0; i < K; i++) etr[i] = __expf(tr[i]);
    float alpha = act ? (start[j] + em_s[j]) : 0.f;
    float emv = act ? em_s[K + j] : 0.f;
    for (int t = 1; t < cnt; t++) {
      float emv_n = (act && (t + 1) < cnt) ? em_s[(t + 1) * K + j] : 0.f;
      float m0 = readlane_f(alpha, 0);
      float ee = __expf(alpha - m0);
      float e0 = readlane_f(ee, 0),  e1 = readlane_f(ee, 1),  e2 = readlane_f(ee, 2);
      float e3 = readlane_f(ee, 3),  e4 = readlane_f(ee, 4),  e5 = readlane_f(ee, 5);
      float e6 = readlane_f(ee, 6),  e7 = readlane_f(ee, 7),  e8 = readlane_f(ee, 8);
      float e9 = readlane_f(ee, 9),  e10 = readlane_f(ee, 10), e11 = readlane_f(ee, 11);
      float e12 = readlane_f(ee, 12), e13 = readlane_f(ee, 13), e14 = readlane_f(ee, 14);
      float e15 = readlane_f(ee, 15), e16 = readlane_f(ee, 16), e17 = readlane_f(ee, 17);
      float e18 = readlane_f(ee, 18), e19 = readlane_f(ee, 19), e20 = readlane_f(ee, 20);
      float a0 = fmaf(e16, etr[16], fmaf(e12, etr[12], fmaf(e8, etr[8],  fmaf(e4, etr[4], e0 * etr[0]))));
      float a1 = fmaf(e17, etr[17], fmaf(e13, etr[13], fmaf(e9, etr[9],  fmaf(e5, etr[5], e1 * etr[1]))));
      float a2 = fmaf(e18, etr[18], fmaf(e14, etr[14], fmaf(e10, etr[10], fmaf(e6, etr[6], e2 * etr[2]))));
      float a3 = fmaf(e19, etr[19], fmaf(e15, etr[15], fmaf(e11, etr[11], fmaf(e7, etr[7], e3 * etr[3]))));
      float ssum = fmaf(e20, etr[20], (a0 + a1) + (a2 + a3));
      float nxt = __logf(ssum) + m0 + emv;
      if (act) alpha = nxt;
      emv = emv_n;
    }
    float aj = act ? (alpha + endv[j]) : -3.0e38f;
    float mm = aj;
#pragma unroll
    for (int off = 32; off > 0; off >>= 1) mm = fmaxf(mm, __shfl_xor(mm, off));
    float e2v = act ? __expf(aj - mm) : 0.f;
    float s2 = wave_sum_f(e2v);
    float den = __logf(s2) + mm;
    if (j == 0) {
      int tag0 = tb[0];
      float numtot = num + start[tag0] + em_s[tag0] + endv[tb[cnt - 1]];
      parts[b] = numtot - den;
    }
  } else {
    float score = act ? (start[j] + em_s[j]) : 0.f;
    float emv = act ? em_s[K + j] : 0.f;
    for (int t = 1; t < cnt; t++) {
      float emv_n = (act && (t + 1) < cnt) ? em_s[(t + 1) * K + j] : 0.f;
      float c0 = readlane_f(score, 0) + tr[0],   c1 = readlane_f(score, 1) + tr[1];
      float c2 = readlane_f(score, 2) + tr[2],   c3 = readlane_f(score, 3) + tr[3];
      float c4 = readlane_f(score, 4) + tr[4],   c5 = readlane_f(score, 5) + tr[5];
      float c6 = readlane_f(score, 6) + tr[6],   c7 = readlane_f(score, 7) + tr[7];
      float c8 = readlane_f(score, 8) + tr[8],   c9 = readlane_f(score, 9) + tr[9];
      float c10 = readlane_f(score, 10) + tr[10], c11 = readlane_f(score, 11) + tr[11];
      float c12 = readlane_f(score, 12) + tr[12], c13 = readlane_f(score, 13) + tr[13];
      float c14 = readlane_f(score, 14) + tr[14], c15 = readlane_f(score, 15) + tr[15];
      float c16 = readlane_f(score, 16) + tr[16], c17 = readlane_f(score, 17) + tr[17];
      float c18 = readlane_f(score, 18) + tr[18], c19 = readlane_f(score, 19) + tr[19];
      float c20 = readlane_f(score, 20) + tr[20];
      MRG(m0v, m0i, c0, 0, c1, 1)
      MRG(m1v, m1i, c2, 2, c3, 3)
      MRG(m2v, m2i, c4, 4, c5, 5)
      MRG(m3v, m3i, c6, 6, c7, 7)
      MRG(m4v, m4i, c8, 8, c9, 9)
      MRG(m5v, m5i, c10, 10, c11, 11)
      MRG(m6v, m6i, c12, 12, c13, 13)
      MRG(m7v, m7i, c14, 14, c15, 15)
      MRG(m8v, m8i, c16, 16, c17, 17)
      MRG(m9v, m9i, c18, 18, c19, 19)
      MRG(p0v, p0i, m0v, m0i, m1v, m1i)
      MRG(p1v, p1i, m2v, m2i, m3v, m3i)
      MRG(p2v, p2i, m4v, m4i, m5v, m5i)
      MRG(p3v, p3i, m6v, m6i, m7v, m7i)
      MRG(p4v, p4i, m8v, m8i, m9v, m9i)
      MRG(r0v, r0i, p0v, p0i, p1v, p1i)
      MRG(r1v, r1i, p2v, p2i, p3v, p3i)
      MRG(r2v, r2i, p4v, p4i, c20, 20)
      MRG(s0v, s0i, r0v, r0i, r1v, r1i)
      MRG(fv, fi, s0v, s0i, r2v, r2i)
      if (act) {
        hist_s[(t - 1) * K + j] = (unsigned char)fi;
        score = fv + emv;
      }
      emv = emv_n;
    }
    if (act) sc_s[j] = score + endv[j];
    __syncthreads();
    if (j == 0) {
      float best = -3.0e38f;
      int last = 0;
#pragma unroll
      for (int i = 0; i < K; i++)
        if (sc_s[i] > best) { best = sc_s[i]; last = i; }
      for (int t = cnt - 1; t < T; t++) outdec[b * T + t] = (float)last;
      int cur = last;
      for (int t = cnt - 1; t >= 1; t--) {
        cur = hist_s[(t - 1) * K + cur];
        outdec[b * T + (t - 1)] = (float)cur;
      }
    }
  }
}

__global__ void nll_final_kernel(const float* __restrict__ parts,
                                 float* __restrict__ out) {
  out[0] = -0.25f * (parts[0] + parts[1] + parts[2] + parts[3]);
}

// ---------------- host launcher ----------------
extern "C" void kernel_launch(void* const* d_in, const int* in_sizes, int n_in,
                              void* d_out, int out_size, void* d_ws, size_t ws_size,
                              hipStream_t stream) {
  (void)in_sizes; (void)n_in; (void)out_size; (void)ws_size;
  const int* ids    = (const int*)d_in[0];
  const int* amask  = (const int*)d_in[1];
  const int* labels = (const int*)d_in[3];
  const float* wemb = (const float*)d_in[4];
  const float* pemb = (const float*)d_in[5];
  const float* temb = (const float*)d_in[6];
  const float* eg   = (const float*)d_in[7];
  const float* ebta = (const float*)d_in[8];
  const float* Wqkv = (const float*)d_in[9];
  const float* bqkv = (const float*)d_in[10];
  const float* Wo   = (const float*)d_in[11];
  const float* bo   = (const float*)d_in[12];
  const float* ln1g = (const float*)d_in[13];
  const float* ln1b = (const float*)d_in[14];
  const float* W1   = (const float*)d_in[15];
  const float* b1   = (const float*)d_in[16];
  const float* W2   = (const float*)d_in[17];
  const float* b2   = (const float*)d_in[18];
  const float* ln2g = (const float*)d_in[19];
  const float* ln2b = (const float*)d_in[20];
  const float* Wc   = (const float*)d_in[21];
  const float* bc   = (const float*)d_in[22];
  const float* cst  = (const float*)d_in[23];
  const float* cen  = (const float*)d_in[24];
  const float* ctr  = (const float*)d_in[25];
  float* out = (float*)d_out;

  // workspace layout (float units) — round-10 layout
  float* ws = (float*)d_ws;
  float* fp = ws;
  float* h = fp;                 fp += 1572864;
  unsigned short* hh  = (unsigned short*)fp; fp += 786432;
  unsigned short* hl  = (unsigned short*)fp; fp += 786432;
  unsigned short* qhp = (unsigned short*)fp; fp += 786432;
  unsigned short* qlp = (unsigned short*)fp; fp += 786432;
  unsigned short* khp = (unsigned short*)fp; fp += 786432;
  unsigned short* klp = (unsigned short*)fp; fp += 786432;
  unsigned short* vtp = (unsigned short*)fp; fp += 786432;
  unsigned short* vlp = (unsigned short*)fp; fp += 786432;
  unsigned short* cth = (unsigned short*)fp; fp += 786432;
  unsigned short* ctl = (unsigned short*)fp; fp += 786432;
  float* tmp = fp;               fp += 1572864;
  unsigned short* gh  = (unsigned short*)fp; fp += 3145728;
  unsigned short* gl  = (unsigned short*)fp; fp += 3145728;
  unsigned short* Wth = (unsigned short*)fp; fp += 3538944;
  unsigned short* Wtl = (unsigned short*)fp; fp += 3538944;
  float* em = fp;                fp += 43008;
  float* parts = fp;             fp += 8;
  float* WcT = fp;               fp += 16128;

  embed_ln_kernel<<<BT, 256, 0, stream>>>(ids, wemb, pemb, temb, eg, ebta, h, hh, hl);
  wct_kernel<<<63, 256, 0, stream>>>(Wc, WcT);

  for (int l = 0; l < NLAYER; l++) {
    const float* bqkv_l = bqkv + (size_t)l * 3 * H;
    const float* bo_l   = bo + (size_t)l * H;
    const float* b1_l   = b1 + (size_t)l * 4 * H;
    const float* b2_l   = b2 + (size_t)l * H;

    wconv_kernel<<<6912, 256, 0, stream>>>(
        Wqkv + (size_t)l * H * 3 * H, Wo + (size_t)l * H * H,
        W1 + (size_t)l * H * 4 * H, W2 + (size_t)l * 4 * H * H, Wth, Wtl);

    // QKV projection (M=2048, N=2304): 576 tiles
    gemm_bf3_kernel<2><<<576, 256, 0, stream>>>(
        hh, hl, Wth, Wtl, bqkv_l, nullptr, qhp, qlp, khp, klp,
        vtp, vlp, 3 * H, H, 18);
    attn_kernel<<<384, 256, 0, stream>>>(
        qhp, qlp, khp, klp, vtp, vlp, amask, cth, ctl);
    // output projection (N=768): 192 tiles
    gemm_bf3_kernel<0><<<192, 256, 0, stream>>>(
        cth, ctl, Wth + 1769472, Wtl + 1769472, bo_l, tmp,
        nullptr, nullptr, nullptr, nullptr, nullptr, nullptr, H, H, 6);
    add_ln_kernel<<<BT, 256, 0, stream>>>(h, tmp, ln1g + (size_t)l * H, ln1b + (size_t)l * H, hh, hl);
    // FFN1 (N=3072): 768 tiles
    gemm_bf3_kernel<1><<<768, 256, 0, stream>>>(
        hh, hl, Wth + 2359296, Wtl + 2359296, b1_l, nullptr, gh, gl,
        nullptr, nullptr, nullptr, nullptr, 4 * H, H, 24);
    // FFN2 (N=768, K=3072): 192 tiles
    gemm_bf3_kernel<0><<<192, 256, 0, stream>>>(
        gh, gl, Wth + 4718592, Wtl + 4718592, b2_l, tmp,
        nullptr, nullptr, nullptr, nullptr, nullptr, nullptr, H, 4 * H, 6);
    add_ln_kernel<<<BT, 256, 0, stream>>>(h, tmp, ln2g + (size_t)l * H, ln2b + (size_t)l * H, hh, hl);
  }

  classifier_kernel<<<(BT * K + 255) / 256, 256, 0, stream>>>(h, WcT, bc, em);
  crf_fused_kernel<<<8, 64, 0, stream>>>(em, labels, amask, cst, cen, ctr, parts, out + 1);
  nll_final_kernel<<<1, 1, 0, stream>>>(parts, out);
}